// Round 1
// baseline (2175.266 us; speedup 1.0000x reference)
//
#include <hip/hip_runtime.h>
#include <hip/hip_bf16.h>

// Problem constants
#define B_   64
#define C_   3
#define NWIN 232
#define TSTEPS 8
#define CHUNK 29
#define DP_  13
#define HP_  32
#define WP_  32
#define IN_DIM 1024
#define H0_  512
#define H1_  512
#define H2_  256
#define CD_  39          // C_*DP_
#define M_   (B_*CD_)    // 2496
#define FEAT 9984        // CD_*H2_
#define NCLS 4

// ---------------------------------------------------------------------------
// Pooling: for one timestep t, read x[b][c][t*29+f][h][w] and produce
// xt[(b*39 + c*13 + dp)*1024 + hp*32 + wp] = avg over (4,2,2) window /16.
// One thread per (b,c,hp,wp); each thread reads 29 frames' 2x2 patch once
// (single-pass over input) and accumulates into 13 depth windows.
// ---------------------------------------------------------------------------
__global__ __launch_bounds__(256) void pool_kernel(const float* __restrict__ x,
                                                   float* __restrict__ xt, int t) {
    int tid = blockIdx.x * 256 + threadIdx.x;   // < 64*3*32*32 = 196608
    int wp = tid & 31;
    int hp = (tid >> 5) & 31;
    int v  = tid >> 10;
    int c  = v % 3;
    int b  = v / 3;

    const float* base = x + (((size_t)(b * 3 + c) * NWIN + t * CHUNK) * 64 + hp * 2) * 64 + wp * 2;

    float acc[DP_];
#pragma unroll
    for (int d = 0; d < DP_; d++) acc[d] = 0.f;

#pragma unroll
    for (int f = 0; f < CHUNK; f++) {
        const float* p = base + (size_t)f * 4096;
        float2 r0 = *(const float2*)p;
        float2 r1 = *(const float2*)(p + 64);
        float fs = (r0.x + r0.y) + (r1.x + r1.y);
        int dplo = (f >= 3) ? ((f - 2) >> 1) : 0;   // ceil((f-3)/2)
        int dphi = (f >> 1) > 12 ? 12 : (f >> 1);
#pragma unroll
        for (int d = dplo; d <= dphi; d++) acc[d] += fs;
    }

    float* o = xt + (size_t)(b * CD_ + c * DP_) * IN_DIM + hp * 32 + wp;
#pragma unroll
    for (int d = 0; d < DP_; d++) o[(size_t)d * IN_DIM] = acc[d] * (1.f / 16.f);
}

// ---------------------------------------------------------------------------
// Fused GEMM (NT: cur[m][n] = sum_k A[m][k]*W[n][k] + bias[n]) + LIF update.
//   reset = (mem > thr); mem_new = 0.9*mem + cur - reset*thr;
//   spk = (mem_new - thr) > 0
// Tiles: BM=BN=64, BK=16, 256 threads, 4x4 micro-tile, LDS transposed with
// stride 68 (16B-aligned rows, conflict-mitigating).
// ---------------------------------------------------------------------------
#define LDSS 68
__global__ __launch_bounds__(256) void gemm_lif(const float* __restrict__ A,
                                                const float* __restrict__ W,
                                                const float* __restrict__ bias,
                                                float* __restrict__ mem,
                                                float* __restrict__ spk,
                                                int N, int K, float thr) {
    __shared__ float As[16][LDSS];
    __shared__ float Ws[16][LDSS];

    int tid = threadIdx.x;
    int bm = blockIdx.y;          // M tile (M = 2496, 39 tiles)
    int bn = blockIdx.x;          // N tile

    int lrow = tid >> 2;          // 0..63
    int lkq  = tid & 3;           // 0..3 (float4 along K)

    const float* Ap = A + (size_t)(bm * 64 + lrow) * K + lkq * 4;
    const float* Wp = W + (size_t)(bn * 64 + lrow) * K + lkq * 4;

    int tm = tid & 15;            // 0..15
    int tn = tid >> 4;            // 0..15

    float acc[4][4];
#pragma unroll
    for (int i = 0; i < 4; i++)
#pragma unroll
        for (int j = 0; j < 4; j++) acc[i][j] = 0.f;

    for (int kt = 0; kt < K; kt += 16) {
        float4 a = *(const float4*)(Ap + kt);
        float4 w = *(const float4*)(Wp + kt);
        As[lkq * 4 + 0][lrow] = a.x;
        As[lkq * 4 + 1][lrow] = a.y;
        As[lkq * 4 + 2][lrow] = a.z;
        As[lkq * 4 + 3][lrow] = a.w;
        Ws[lkq * 4 + 0][lrow] = w.x;
        Ws[lkq * 4 + 1][lrow] = w.y;
        Ws[lkq * 4 + 2][lrow] = w.z;
        Ws[lkq * 4 + 3][lrow] = w.w;
        __syncthreads();
#pragma unroll
        for (int k = 0; k < 16; k++) {
            float4 av = *(const float4*)&As[k][tm * 4];
            float4 bv = *(const float4*)&Ws[k][tn * 4];
            float aa[4] = {av.x, av.y, av.z, av.w};
            float bb[4] = {bv.x, bv.y, bv.z, bv.w};
#pragma unroll
            for (int i = 0; i < 4; i++)
#pragma unroll
                for (int j = 0; j < 4; j++) acc[i][j] += aa[i] * bb[j];
        }
        __syncthreads();
    }

    // Epilogue: bias + LIF
#pragma unroll
    for (int i = 0; i < 4; i++) {
        int m = bm * 64 + tm * 4 + i;
#pragma unroll
        for (int j = 0; j < 4; j++) {
            int n = bn * 64 + tn * 4 + j;
            float cur = acc[i][j] + bias[n];
            size_t idx = (size_t)m * N + n;
            float mv = mem[idx];
            float reset = (mv > thr) ? 1.f : 0.f;
            float mn = 0.9f * mv + cur - reset * thr;
            mem[idx] = mn;
            spk[idx] = ((mn - thr) > 0.f) ? 1.f : 0.f;
        }
    }
}

// ---------------------------------------------------------------------------
// Output layer: cur[b][n] = sum_k s2[b][k]*W_out[n][k] + b_out[n], then LIF
// with thr=1.0; write spikes to d_out[t][b][n]. One block per batch element.
// ---------------------------------------------------------------------------
__global__ __launch_bounds__(256) void out_kernel(const float* __restrict__ s2,
                                                  const float* __restrict__ Wout,
                                                  const float* __restrict__ bout,
                                                  float* __restrict__ m_out,
                                                  float* __restrict__ out, int t) {
    int b = blockIdx.x;
    int tid = threadIdx.x;
    const float* s = s2 + (size_t)b * FEAT;
    float a0 = 0.f, a1 = 0.f, a2 = 0.f, a3 = 0.f;
    for (int k = tid; k < FEAT; k += 256) {
        float a = s[k];
        a0 += a * Wout[k];
        a1 += a * Wout[FEAT + k];
        a2 += a * Wout[2 * FEAT + k];
        a3 += a * Wout[3 * FEAT + k];
    }
    __shared__ float red[4][256];
    red[0][tid] = a0; red[1][tid] = a1; red[2][tid] = a2; red[3][tid] = a3;
    __syncthreads();
    for (int sft = 128; sft > 0; sft >>= 1) {
        if (tid < sft) {
#pragma unroll
            for (int n = 0; n < 4; n++) red[n][tid] += red[n][tid + sft];
        }
        __syncthreads();
    }
    if (tid < 4) {
        float cur = red[tid][0] + bout[tid];
        float mv = m_out[b * 4 + tid];
        float reset = (mv > 1.0f) ? 1.f : 0.f;
        float mn = 0.9f * mv + cur - reset * 1.0f;
        m_out[b * 4 + tid] = mn;
        out[t * (B_ * NCLS) + b * 4 + tid] = ((mn - 1.0f) > 0.f) ? 1.f : 0.f;
    }
}

extern "C" void kernel_launch(void* const* d_in, const int* in_sizes, int n_in,
                              void* d_out, int out_size, void* d_ws, size_t ws_size,
                              hipStream_t stream) {
    const float* x     = (const float*)d_in[0];
    const float* W_in  = (const float*)d_in[1];
    const float* b_in  = (const float*)d_in[2];
    const float* W_h1  = (const float*)d_in[3];
    const float* b_h1  = (const float*)d_in[4];
    const float* W_h2  = (const float*)d_in[5];
    const float* b_h2  = (const float*)d_in[6];
    const float* W_out = (const float*)d_in[7];
    const float* b_out = (const float*)d_in[8];

    float* ws  = (float*)d_ws;
    float* xt  = ws;                        // 2496*1024 = 2,555,904
    float* s0  = xt  + (size_t)M_ * IN_DIM; // 2496*512
    float* s1  = s0  + (size_t)M_ * H0_;    // 2496*512
    float* s2  = s1  + (size_t)M_ * H1_;    // 2496*256
    float* m_in = s2  + (size_t)M_ * H2_;   // 2496*512
    float* m_h1 = m_in + (size_t)M_ * H0_;  // 2496*512
    float* m_h2 = m_h1 + (size_t)M_ * H1_;  // 2496*256
    float* m_o  = m_h2 + (size_t)M_ * H2_;  // 256

    // zero all membrane state (harness poisons d_ws each call)
    size_t memBytes = ((size_t)M_ * (H0_ + H1_ + H2_) + B_ * NCLS) * sizeof(float);
    hipMemsetAsync(m_in, 0, memBytes, stream);

    for (int t = 0; t < TSTEPS; t++) {
        pool_kernel<<<(B_ * C_ * HP_ * WP_) / 256, 256, 0, stream>>>(x, xt, t);
        gemm_lif<<<dim3(H0_ / 64, M_ / 64), 256, 0, stream>>>(xt, W_in, b_in, m_in, s0, H0_, IN_DIM, 0.5f);
        gemm_lif<<<dim3(H1_ / 64, M_ / 64), 256, 0, stream>>>(s0, W_h1, b_h1, m_h1, s1, H1_, H0_, 0.5f);
        gemm_lif<<<dim3(H2_ / 64, M_ / 64), 256, 0, stream>>>(s1, W_h2, b_h2, m_h2, s2, H2_, H1_, 0.5f);
        out_kernel<<<B_, 256, 0, stream>>>(s2, W_out, b_out, m_o, (float*)d_out, t);
    }
}

// Round 2
// 2103.498 us; speedup vs baseline: 1.0341x; 1.0341x over previous
//
#include <hip/hip_runtime.h>
#include <hip/hip_bf16.h>

// Problem constants
#define B_   64
#define C_   3
#define NWIN 232
#define TSTEPS 8
#define CHUNK 29
#define DP_  13
#define HP_  32
#define WP_  32
#define IN_DIM 1024
#define H0_  512
#define H1_  512
#define H2_  256
#define CD_  39            // C_*DP_
#define M_   (B_*CD_)      // 2496
#define MPAD 2560          // padded to 64*40
#define FEAT 9984
#define NCLS 4
#define BETA 0.9f

typedef unsigned short ushort_t;
typedef short s16x8 __attribute__((ext_vector_type(8)));
typedef float f32x4 __attribute__((ext_vector_type(4)));

__device__ __forceinline__ ushort_t f2bf(float f) {
    unsigned int u = __float_as_uint(f);
    unsigned int r = u + 0x7FFFu + ((u >> 16) & 1u);
    return (ushort_t)(r >> 16);
}
__device__ __forceinline__ float bf2f(ushort_t h) {
    return __uint_as_float(((unsigned int)h) << 16);
}

// ---------------------------------------------------------------------------
// Weight split: out rows of length (dup?3K:2K): [W_hi | W_lo (| W_hi)]
// ---------------------------------------------------------------------------
__global__ __launch_bounds__(256) void split_w(const float* __restrict__ W,
                                               ushort_t* __restrict__ out,
                                               int N, int K, int dup) {
    int i = blockIdx.x * 256 + threadIdx.x;
    if (i >= N * K) return;
    int n = i / K, k = i - n * K;
    float w = W[i];
    ushort_t hi = f2bf(w);
    ushort_t lo = f2bf(w - bf2f(hi));
    size_t rb = (size_t)n * (size_t)(dup ? 3 * K : 2 * K);
    out[rb + k] = hi;
    out[rb + K + k] = lo;
    if (dup) out[rb + 2 * K + k] = hi;
}

// ---------------------------------------------------------------------------
// Pool for ALL timesteps: x[b][c][t*29+f][h][w] -> xt2[t][m][kcol] with
// m = b*39 + c*13 + dp (rows padded to MPAD), kcol layout per row (3072):
//   [0..1023]=hi, [1024..2047]=hi (dup), [2048..3071]=lo
// ---------------------------------------------------------------------------
__global__ __launch_bounds__(256) void pool_all(const float* __restrict__ x,
                                                ushort_t* __restrict__ xt2) {
    int v = blockIdx.x * 256 + threadIdx.x;    // < 8*64*3*32*32
    int wp = v & 31;
    int hp = (v >> 5) & 31;
    int u = v >> 10;
    int c = u % 3; u /= 3;
    int b = u % 64;
    int t = u / 64;

    const float* base = x + (((size_t)(b * 3 + c) * NWIN + t * CHUNK) * 64 + hp * 2) * 64 + wp * 2;

    float acc[DP_];
#pragma unroll
    for (int d = 0; d < DP_; d++) acc[d] = 0.f;

#pragma unroll
    for (int f = 0; f < CHUNK; f++) {
        const float* p = base + (size_t)f * 4096;
        float2 r0 = *(const float2*)p;
        float2 r1 = *(const float2*)(p + 64);
        float fs = (r0.x + r0.y) + (r1.x + r1.y);
        int dplo = (f >= 3) ? ((f - 2) >> 1) : 0;
        int dphi = (f >> 1) > 12 ? 12 : (f >> 1);
#pragma unroll
        for (int d = dplo; d <= dphi; d++) acc[d] += fs;
    }

    ushort_t* o = xt2 + (size_t)t * MPAD * 3072
                      + (size_t)(b * CD_ + c * DP_) * 3072 + hp * 32 + wp;
#pragma unroll
    for (int d = 0; d < DP_; d++) {
        float a = acc[d] * (1.f / 16.f);
        ushort_t hi = f2bf(a);
        ushort_t lo = f2bf(a - bf2f(hi));
        o[(size_t)d * 3072] = hi;
        o[(size_t)d * 3072 + 1024] = hi;
        o[(size_t)d * 3072 + 2048] = lo;
    }
}

// ---------------------------------------------------------------------------
// bf16 MFMA GEMM (NT) + LIF epilogue.
//   cur[m][n] = sum_k A[m][k]*W[n][k] + bias[n]
//   reset=(mem>thr); mem=BETA*mem+cur-reset*thr; spk=(mem-thr)>0 (as bf16 0/1)
// BM=BN=64, BK=64, 256 threads (4 waves, 32x32 quadrant each),
// MFMA 16x16x32 bf16. LDS holds tiles in FRAGMENT ORDER:
//   frag(mt,kb) : 1KB block, lane-major, lane=(r&15)+16*((k%32)/8)
// so compute reads are contiguous ds_read_b128 at lane*16.
// spk written to spk[m*spkStride+n] and (if dupOff) +dupOff (K-duplication
// for the next layer's [S|S] input).
// ---------------------------------------------------------------------------
__global__ __launch_bounds__(256) void gemm_lif(const ushort_t* __restrict__ A,
                                                const ushort_t* __restrict__ W2,
                                                const float* __restrict__ bias,
                                                float* __restrict__ mem,
                                                ushort_t* __restrict__ spk,
                                                int K, int N, int spkStride,
                                                int dupOff, float thr) {
    __shared__ __align__(16) ushort_t Als[8 * 512];   // 8 frags x 1KB
    __shared__ __align__(16) ushort_t Wls[8 * 512];

    int tid = threadIdx.x;
    int bn = blockIdx.x;              // N tile
    int bm = blockIdx.y;              // M tile (40)
    int rowBase = bm * 64;
    int colBase = bn * 64;

    int w = tid >> 6;                 // wave 0..3
    int lane = tid & 63;
    int wm = w >> 1;                  // row half
    int wn = w & 1;                   // col half

    // staging coords
    int sr = tid >> 3;                // 0..31 (+32 on pass 1)
    int scg = tid & 7;                // col-group of 8 bf16
    int skb = scg >> 2;               // k-block 0..1
    int slq = scg & 3;                // lane quad
    // frag slot this thread's 16B belongs to (row part varies per pass)

    f32x4 acc[2][2];
#pragma unroll
    for (int i = 0; i < 2; i++)
#pragma unroll
        for (int j = 0; j < 2; j++) acc[i][j] = (f32x4)(0.f);

    for (int kt = 0; kt < K; kt += 64) {
#pragma unroll
        for (int p = 0; p < 2; p++) {
            int r = sr + p * 32;
            int fl = (r & 15) + 16 * slq;
            int fr = (r >> 4) * 2 + skb;
            uint4 va = *(const uint4*)(A + (size_t)(rowBase + r) * K + kt + scg * 8);
            uint4 vw = *(const uint4*)(W2 + (size_t)(colBase + r) * K + kt + scg * 8);
            *(uint4*)(&Als[fr * 512 + fl * 8]) = va;
            *(uint4*)(&Wls[fr * 512 + fl * 8]) = vw;
        }
        __syncthreads();
#pragma unroll
        for (int kb = 0; kb < 2; kb++) {
            s16x8 a0 = *(const s16x8*)(&Als[((wm * 2 + 0) * 2 + kb) * 512 + lane * 8]);
            s16x8 a1 = *(const s16x8*)(&Als[((wm * 2 + 1) * 2 + kb) * 512 + lane * 8]);
            s16x8 b0 = *(const s16x8*)(&Wls[((wn * 2 + 0) * 2 + kb) * 512 + lane * 8]);
            s16x8 b1 = *(const s16x8*)(&Wls[((wn * 2 + 1) * 2 + kb) * 512 + lane * 8]);
            acc[0][0] = __builtin_amdgcn_mfma_f32_16x16x32_bf16(a0, b0, acc[0][0], 0, 0, 0);
            acc[0][1] = __builtin_amdgcn_mfma_f32_16x16x32_bf16(a0, b1, acc[0][1], 0, 0, 0);
            acc[1][0] = __builtin_amdgcn_mfma_f32_16x16x32_bf16(a1, b0, acc[1][0], 0, 0, 0);
            acc[1][1] = __builtin_amdgcn_mfma_f32_16x16x32_bf16(a1, b1, acc[1][1], 0, 0, 0);
        }
        __syncthreads();
    }

    // Epilogue: C/D layout col=lane&15, row=(lane>>4)*4+reg
    int ccol = lane & 15;
    int crow = (lane >> 4) * 4;
#pragma unroll
    for (int mt = 0; mt < 2; mt++) {
#pragma unroll
        for (int nt = 0; nt < 2; nt++) {
            int col = colBase + wn * 32 + nt * 16 + ccol;
            int row0 = rowBase + wm * 32 + mt * 16 + crow;
            float bv = bias[col];
#pragma unroll
            for (int reg = 0; reg < 4; reg++) {
                int r = row0 + reg;
                float cur = acc[mt][nt][reg] + bv;
                size_t mi = (size_t)r * N + col;
                float mv = mem[mi];
                float reset = (mv > thr) ? 1.f : 0.f;
                float mn = BETA * mv + cur - reset * thr;
                mem[mi] = mn;
                ushort_t s = ((mn - thr) > 0.f) ? (ushort_t)0x3F80 : (ushort_t)0;
                size_t si = (size_t)r * spkStride + col;
                spk[si] = s;
                if (dupOff) spk[si + dupOff] = s;
            }
        }
    }
}

// ---------------------------------------------------------------------------
// Output layer: cur[b][n] = sum_k s2row[k]*W_out[n][k] + b_out[n]; LIF thr=1.
// s2 is bf16 [MPAD][256]; batch b's features = rows b*39..b*39+38 flattened.
// ---------------------------------------------------------------------------
__global__ __launch_bounds__(256) void out_kernel(const ushort_t* __restrict__ s2,
                                                  const float* __restrict__ Wout,
                                                  const float* __restrict__ bout,
                                                  float* __restrict__ m_out,
                                                  float* __restrict__ out, int t) {
    int b = blockIdx.x;
    int tid = threadIdx.x;
    const ushort_t* s = s2 + (size_t)b * CD_ * H2_;
    float a0 = 0.f, a1 = 0.f, a2 = 0.f, a3 = 0.f;
    for (int k = tid; k < FEAT; k += 256) {
        float a = bf2f(s[k]);
        a0 += a * Wout[k];
        a1 += a * Wout[FEAT + k];
        a2 += a * Wout[2 * FEAT + k];
        a3 += a * Wout[3 * FEAT + k];
    }
    __shared__ float red[4][256];
    red[0][tid] = a0; red[1][tid] = a1; red[2][tid] = a2; red[3][tid] = a3;
    __syncthreads();
    for (int sft = 128; sft > 0; sft >>= 1) {
        if (tid < sft) {
#pragma unroll
            for (int n = 0; n < 4; n++) red[n][tid] += red[n][tid + sft];
        }
        __syncthreads();
    }
    if (tid < 4) {
        float cur = red[tid][0] + bout[tid];
        float mv = m_out[b * 4 + tid];
        float reset = (mv > 1.0f) ? 1.f : 0.f;
        float mn = BETA * mv + cur - reset * 1.0f;
        m_out[b * 4 + tid] = mn;
        out[t * (B_ * NCLS) + b * 4 + tid] = ((mn - 1.0f) > 0.f) ? 1.f : 0.f;
    }
}

extern "C" void kernel_launch(void* const* d_in, const int* in_sizes, int n_in,
                              void* d_out, int out_size, void* d_ws, size_t ws_size,
                              hipStream_t stream) {
    const float* x     = (const float*)d_in[0];
    const float* W_in  = (const float*)d_in[1];
    const float* b_in  = (const float*)d_in[2];
    const float* W_h1  = (const float*)d_in[3];
    const float* b_h1  = (const float*)d_in[4];
    const float* W_h2  = (const float*)d_in[5];
    const float* b_h2  = (const float*)d_in[6];
    const float* W_out = (const float*)d_in[7];
    const float* b_out = (const float*)d_in[8];

    char* p = (char*)d_ws;
    ushort_t* xt2  = (ushort_t*)p; p += (size_t)TSTEPS * MPAD * 3072 * 2;  // 125.8 MB
    ushort_t* W2i  = (ushort_t*)p; p += (size_t)H0_ * 3072 * 2;            // 3.1 MB
    ushort_t* W2h1 = (ushort_t*)p; p += (size_t)H1_ * 1024 * 2;            // 1.0 MB
    ushort_t* W2h2 = (ushort_t*)p; p += (size_t)H2_ * 1024 * 2;            // 0.5 MB
    ushort_t* s0   = (ushort_t*)p; p += (size_t)MPAD * 1024 * 2;           // 5.2 MB
    ushort_t* s1   = (ushort_t*)p; p += (size_t)MPAD * 1024 * 2;
    ushort_t* s2   = (ushort_t*)p; p += (size_t)MPAD * 256 * 2;
    float* m_in = (float*)p; p += (size_t)MPAD * H0_ * 4;
    float* m_h1 = (float*)p; p += (size_t)MPAD * H1_ * 4;
    float* m_h2 = (float*)p; p += (size_t)MPAD * H2_ * 4;
    float* m_o  = (float*)p; p += (size_t)B_ * NCLS * 4;

    // zero all membrane state (contiguous region)
    size_t memBytes = ((size_t)MPAD * (H0_ + H1_ + H2_) + B_ * NCLS) * sizeof(float);
    hipMemsetAsync(m_in, 0, memBytes, stream);

    split_w<<<(H0_ * IN_DIM + 255) / 256, 256, 0, stream>>>(W_in, W2i, H0_, IN_DIM, 1);
    split_w<<<(H1_ * H0_ + 255) / 256, 256, 0, stream>>>(W_h1, W2h1, H1_, H0_, 0);
    split_w<<<(H2_ * H1_ + 255) / 256, 256, 0, stream>>>(W_h2, W2h2, H2_, H1_, 0);

    pool_all<<<(TSTEPS * B_ * C_ * HP_ * WP_) / 256, 256, 0, stream>>>(x, xt2);

    for (int t = 0; t < TSTEPS; t++) {
        const ushort_t* At = xt2 + (size_t)t * MPAD * 3072;
        gemm_lif<<<dim3(H0_ / 64, MPAD / 64), 256, 0, stream>>>(
            At, W2i, b_in, m_in, s0, 3072, H0_, 1024, 512, 0.5f);
        gemm_lif<<<dim3(H1_ / 64, MPAD / 64), 256, 0, stream>>>(
            s0, W2h1, b_h1, m_h1, s1, 1024, H1_, 1024, 512, 0.5f);
        gemm_lif<<<dim3(H2_ / 64, MPAD / 64), 256, 0, stream>>>(
            s1, W2h2, b_h2, m_h2, s2, 1024, H2_, 256, 0, 0.5f);
        out_kernel<<<B_, 256, 0, stream>>>(s2, W_out, b_out, m_o, (float*)d_out, t);
    }
}